// Round 15
// baseline (2069.755 us; speedup 1.0000x reference)
//
#include <hip/hip_runtime.h>
#include <cstdint>
#include <cstddef>

// =====================================================================
// RBM Gibbs sampling, bit-exact replication of JAX-on-CPU reference.
// ROUND 25 (perf): force v_pk_fma_f32 via inline asm. R24 post-mortem:
// hpart & gemm_v share a VALU plateau (busy 190-205us vs 68us packed
// floor); R19/R20/R24 busy-time cross-check matches SCALARIZED fma
// (136us floor + overhead), i.e. __builtin_elementwise_fma on our
// mk2()-assembled f32x2 is scalar-lowered. Fix: pkfma = inline asm
// "v_pk_fma_f32 %0,%1,%2,%3" (no modifiers = natural SIMD: lo=fma of
// lo halves, hi=fma of hi halves -- the exact same two IEEE fmaf's,
// bit-identical). Non-volatile pure asm (schedulable, CSE-able).
// Everything else = R24 verbatim (passed): c-split gemm_v (grid 5120),
// hpart 32b grid 4096 10KB LDS, hfin/idxT/gumbel/idx/wt/onehot.
// Bit-exactness: per-(b,v)/(b,h) fma chains byte-identical (h/k
// ascending); k-split legal via sequential slab folds (tt += ps[s],
// s asc); dense +/-0.0 adds identities on never--0.0 psums; phantom
// 9th panel = +0.0; sums f32 round-trip exact; gumbel expressions/
// RNG indices identical.
// Semantics FROZEN (rounds 6-20,22-24 passed, absmax=0):
//  - threefry2x32 partitionable; fold-like split; seed(42)->(0,42).
//  - cephes-Horner exp, Pommier-Horner log (q1/q2 tail), no contract.
//  - sigmoid = 1/(1+exp(-x)) IEEE div; gumbel tiny-clamp; first-max
//    argmax; bernoulli u<p; v-GEMM K=256 single sequential chain.
//  - h-GEMM: Eigen gebp kc=320 slab fold, k ascending (c-major).
// ws layout unchanged; sentinel reads back ws_size as absmax if short.
// =====================================================================

#define B_DIM 16384
#define C_DIM 5
#define H_DIM 256
#define V_DIM 512

struct TFOut { uint32_t a, b; };

typedef float f32x2 __attribute__((ext_vector_type(2)));
typedef float f32x4 __attribute__((ext_vector_type(4)));

static __device__ inline f32x2 mk2(float x, float y) {
  f32x2 r; r.x = x; r.y = y; return r;
}

// Forced packed fma: D.lo = fma(a.lo,b.lo,c.lo), D.hi = fma(a.hi,b.hi,c.hi)
// (default op_sel/op_sel_hi = natural SIMD). Bit-identical to two fmaf's.
static __device__ inline f32x2 pkfma(f32x2 a, f32x2 b, f32x2 c) {
  f32x2 d;
  asm("v_pk_fma_f32 %0, %1, %2, %3" : "=v"(d) : "v"(a), "v"(b), "v"(c));
  return d;
}

__host__ __device__ static inline TFOut tf2x32(uint32_t k0, uint32_t k1,
                                               uint32_t c0, uint32_t c1) {
  uint32_t ks2 = k0 ^ k1 ^ 0x1BD11BDAu;
  uint32_t x0 = c0 + k0, x1 = c1 + k1;
#define TF_R(r) { x0 += x1; x1 = (x1 << r) | (x1 >> (32 - r)); x1 ^= x0; }
  TF_R(13) TF_R(15) TF_R(26) TF_R(6)
  x0 += k1;  x1 += ks2 + 1u;
  TF_R(17) TF_R(29) TF_R(16) TF_R(24)
  x0 += ks2; x1 += k0 + 2u;
  TF_R(13) TF_R(15) TF_R(26) TF_R(6)
  x0 += k0;  x1 += k1 + 3u;
  TF_R(17) TF_R(29) TF_R(16) TF_R(24)
  x0 += k1;  x1 += ks2 + 4u;
  TF_R(13) TF_R(15) TF_R(26) TF_R(6)
  x0 += ks2; x1 += k0 + 5u;
#undef TF_R
  TFOut o; o.a = x0; o.b = x1; return o;
}

// partitionable random_bits, 32-bit width, element index i (< 2^32)
__device__ static inline uint32_t rng_bits(uint32_t k0, uint32_t k1, uint32_t i) {
  TFOut r = tf2x32(k0, k1, 0u, i);
  return r.a ^ r.b;
}

__device__ static inline float bits_to_unit_float(uint32_t bits) {
  return __uint_as_float((bits >> 9) | 0x3F800000u) - 1.0f;
}

// XLA GenerateVF32Exp replica (cephes Horner port), mul+add separate,
// NO contraction.
__device__ static float xla_exp(float x_in) {
#pragma clang fp contract(off)
  float x = fminf(x_in, 88.3762626647950f);
  x = fmaxf(x, -88.3762626647949f);
  float fx = floorf(x * 1.44269504088896341f + 0.5f);
  float tmp = fx * 0.693359375f;
  float z = fx * -2.12194440e-4f;
  x = x - tmp;
  x = x - z;
  z = x * x;
  float y = 1.9875691500e-4f;
  y = y * x + 1.3981999507e-3f;
  y = y * x + 8.3334519073e-3f;
  y = y * x + 4.1665795894e-2f;
  y = y * x + 1.6666665459e-1f;
  y = y * x + 5.0000001201e-1f;
  y = y * z + x;
  y = y + 1.0f;
  int n = (int)fx;
  y = y * __uint_as_float((uint32_t)(n + 127) << 23);
  return y;
}

// XLA GenerateVF32Log replica = Pommier/Eigen3.3 log_ps (Horner + tail:
// y+=e*q1; y-=0.5*z; x+=y; x+=e*q2). NO contraction.
__device__ static float xla_log(float x_in) {
#pragma clang fp contract(off)
  float xv = fmaxf(x_in, 1.17549435e-38f);      // min_norm_pos clamp
  uint32_t bits = __float_as_uint(xv);
  float e = (float)((int)(bits >> 23) - 126);
  float x = __uint_as_float((bits & 0x007FFFFFu) | 0x3F000000u);  // [0.5,1)
  bool m = (x < 0.707106781186547524f);
  float tmp = m ? x : 0.0f;
  x = x - 1.0f;
  e = e - (m ? 1.0f : 0.0f);
  x = x + tmp;
  float z = x * x;
  float y = 7.0376836292e-2f;
  y = y * x + -1.1514610310e-1f;
  y = y * x + 1.1676998740e-1f;
  y = y * x + -1.2420140846e-1f;
  y = y * x + 1.4249322787e-1f;
  y = y * x + -1.6668057665e-1f;
  y = y * x + 2.0000714765e-1f;
  y = y * x + -2.4999993993e-1f;
  y = y * x + 3.3333331174e-1f;
  y = y * x;
  y = y * z;
  float t1 = e * -2.12194440e-4f;
  y = y + t1;
  float t2 = z * 0.5f;
  y = y - t2;
  x = x + y;
  float t3 = e * 0.693359375f;
  x = x + t3;
  return x;
}

// ---------------- kernels ----------------

__global__ void k_sentinel(float* out, float d) {
  out[0] = d;
}

// v0 one-hot (B,C,V) -> idx (B,V) u8
__global__ __launch_bounds__(256) void k_idx(const float* __restrict__ v0,
                                             uint8_t* __restrict__ idx) {
  int t = blockIdx.x * 256 + threadIdx.x;          // b*V + v
  int b = t >> 9, v = t & 511;
  const float* p = v0 + (size_t)b * (C_DIM * V_DIM) + v;
  int cf = 0;
#pragma unroll
  for (int c = 0; c < C_DIM; ++c)
    if (p[c * V_DIM] > 0.5f) cf = c;
  idx[t] = (uint8_t)cf;
}

// idx (B,V) u8 -> idxT (V,B) u8 via 64x64 LDS tiles (coalesced both ways)
__global__ __launch_bounds__(256) void k_idxT(const uint8_t* __restrict__ idx,
                                              uint8_t* __restrict__ idxT) {
  __shared__ uint8_t tile[64][68];
  int t = threadIdx.x;
  int bb = blockIdx.x >> 3, vv = blockIdx.x & 7;
  int b0 = bb * 64, v0 = vv * 64;
  for (int i = t; i < 1024; i += 256) {        // 64 b-rows x 16 u32
    int r = i >> 4, wc = i & 15;
    uint32_t q = *(const uint32_t*)(idx + (size_t)(b0 + r) * V_DIM + v0 + wc * 4);
    int v = wc * 4;
    tile[v + 0][r] = (uint8_t)(q);
    tile[v + 1][r] = (uint8_t)(q >> 8);
    tile[v + 2][r] = (uint8_t)(q >> 16);
    tile[v + 3][r] = (uint8_t)(q >> 24);
  }
  __syncthreads();
  for (int i = t; i < 1024; i += 256) {        // 64 v-rows x 16 u32
    int vr = i >> 4, wc = i & 15;
    uint32_t q = (uint32_t)tile[vr][wc * 4]
               | ((uint32_t)tile[vr][wc * 4 + 1] << 8)
               | ((uint32_t)tile[vr][wc * 4 + 2] << 16)
               | ((uint32_t)tile[vr][wc * 4 + 3] << 24);
    *(uint32_t*)(idxT + (size_t)(v0 + vr) * B_DIM + b0 + wc * 4) = q;
  }
}

// W (c,h,v) -> Wt (c,v,h)
__global__ __launch_bounds__(256) void k_wt(const float* __restrict__ W,
                                            float* __restrict__ Wt) {
  int t = blockIdx.x * 256 + threadIdx.x;          // (c, v, h)
  int h = t & 255; int rest = t >> 8; int v = rest & 511; int c = rest >> 9;
  Wt[t] = W[((size_t)c * H_DIM + h) * V_DIM + v];
}

// =====================================================================
// k_hpart (R22/R24, passed): partial[s][b][h] = dense k-ascending fma
// psum over slab s (k in [320s, 320s+320)), f = (idxT[k&511][b]==k>>9).
// Block = 32 b x 256 h x 1 slab; thread = 8 b (4 pk pairs) x 4 h.
// Grid 4096 = 512 b-groups x 8 slabs. tbf[80][32] = 10KB LDS.
// psum carries across the 4 sub-tiles (folds only at slab=block
// boundaries) -- chain per (b,h) identical to R18-R24.
// =====================================================================
__global__ __launch_bounds__(256, 4) void k_hpart(
    const float* __restrict__ Wt, const uint8_t* __restrict__ idxT,
    float* __restrict__ partial) {
  __shared__ __align__(16) float tbf[80][32];    // f-floats, one k-tile
  int t = threadIdx.x;
  int bg = blockIdx.x >> 3, s = blockIdx.x & 7;
  int b0 = bg * 32;
  int wv = t >> 6, lane = t & 63;
  int g8 = wv * 8;

  f32x2 ps[4][4];
#pragma unroll
  for (int hq = 0; hq < 4; ++hq)
#pragma unroll
    for (int p = 0; p < 4; ++p) ps[hq][p] = mk2(0.f, 0.f);

  for (int tau = 0; tau < 4; ++tau) {
    int kbase = s * 320 + tau * 80;
    // ---- expand f-floats for this tile (coalesced idxT reads) ----
    {
      int kk0 = t >> 3, bq = t & 7;              // kk0 0..31, bq 0..7
#pragma unroll
      for (int i = 0; i < 3; ++i) {
        int kk = kk0 + 32 * i;
        if (kk < 80) {
          int k = kbase + kk;
          int v = k & 511;
          uint32_t cc = (uint32_t)(k >> 9);
          uint32_t q = *(const uint32_t*)(idxT + (size_t)v * B_DIM + b0 + bq * 4);
          float4 o;
          o.x = ((q & 255u) == cc) ? 1.0f : 0.0f;
          o.y = (((q >> 8) & 255u) == cc) ? 1.0f : 0.0f;
          o.z = (((q >> 16) & 255u) == cc) ? 1.0f : 0.0f;
          o.w = (((q >> 24) & 255u) == cc) ? 1.0f : 0.0f;
          *(float4*)&tbf[kk][bq * 4] = o;
        }
      }
    }
    __syncthreads();
    // ---- dense accumulate over the tile, k ascending ----
#pragma unroll 2
    for (int kk = 0; kk < 80; ++kk) {
      int k = kbase + kk;
      float4 w = *(const float4*)(Wt + (size_t)k * H_DIM + (lane << 2));
      const f32x4* fp = (const f32x4*)&tbf[kk][g8];
      f32x4 qA = fp[0], qB = fp[1];
      f32x2 f0 = __builtin_shufflevector(qA, qA, 0, 1);
      f32x2 f1 = __builtin_shufflevector(qA, qA, 2, 3);
      f32x2 f2 = __builtin_shufflevector(qB, qB, 0, 1);
      f32x2 f3 = __builtin_shufflevector(qB, qB, 2, 3);
      f32x2 w0 = mk2(w.x, w.x);
      f32x2 w1 = mk2(w.y, w.y);
      f32x2 w2 = mk2(w.z, w.z);
      f32x2 w3 = mk2(w.w, w.w);
      ps[0][0] = pkfma(w0, f0, ps[0][0]); ps[1][0] = pkfma(w1, f0, ps[1][0]);
      ps[2][0] = pkfma(w2, f0, ps[2][0]); ps[3][0] = pkfma(w3, f0, ps[3][0]);
      ps[0][1] = pkfma(w0, f1, ps[0][1]); ps[1][1] = pkfma(w1, f1, ps[1][1]);
      ps[2][1] = pkfma(w2, f1, ps[2][1]); ps[3][1] = pkfma(w3, f1, ps[3][1]);
      ps[0][2] = pkfma(w0, f2, ps[0][2]); ps[1][2] = pkfma(w1, f2, ps[1][2]);
      ps[2][2] = pkfma(w2, f2, ps[2][2]); ps[3][2] = pkfma(w3, f2, ps[3][2]);
      ps[0][3] = pkfma(w0, f3, ps[0][3]); ps[1][3] = pkfma(w1, f3, ps[1][3]);
      ps[2][3] = pkfma(w2, f3, ps[2][3]); ps[3][3] = pkfma(w3, f3, ps[3][3]);
    }
    __syncthreads();   // tbf reads done before next tile's expand
  }

  // ---- store partials: pair p covers b = b0+g8+2p (+1 in .y) ----
  int h0 = lane << 2;
#pragma unroll
  for (int p = 0; p < 4; ++p) {
    float4 oA, oB;
    oA.x = ps[0][p].x; oA.y = ps[1][p].x; oA.z = ps[2][p].x; oA.w = ps[3][p].x;
    oB.x = ps[0][p].y; oB.y = ps[1][p].y; oB.z = ps[2][p].y; oB.w = ps[3][p].y;
    int bA = b0 + g8 + 2 * p;
    *(float4*)&partial[((size_t)s * B_DIM + bA) * H_DIM + h0] = oA;
    *(float4*)&partial[((size_t)s * B_DIM + bA + 1) * H_DIM + h0] = oB;
  }
}

// =====================================================================
// k_hfin: fold the 8 slab partials in s-ascending order (exact R11
// chain: tt starts 0, tt += ps[s]; phantom 9th panel = +0.0 identity),
// then sigmoid + bernoulli + out_h + mask (R11 epilogue verbatim).
// =====================================================================
__global__ __launch_bounds__(256) void k_hfin(
    const float* __restrict__ partial, const float* __restrict__ c1,
    float* __restrict__ out_h, uint32_t* __restrict__ out_mask,
    uint32_t key0, uint32_t key1) {
  int b = blockIdx.x;
  int t = threadIdx.x;
  int wv = t >> 6;
  float tt = 0.0f;
#pragma unroll
  for (int s = 0; s < 8; ++s)
    tt = tt + partial[((size_t)s * B_DIM + b) * H_DIM + t];

  float tot = tt + c1[t];
  float p = 1.0f / (1.0f + xla_exp(-tot));   // IEEE div, logistic exp form

  uint32_t i = (uint32_t)(b * H_DIM + t);
  float u = bits_to_unit_float(rng_bits(key0, key1, i));
  bool hb = (u < p);
  if (out_h) out_h[(size_t)b * H_DIM + t] = hb ? 1.0f : 0.0f;

  unsigned long long m = __ballot(hb);
  if ((t & 63) == 0) {
    out_mask[(size_t)b * 8 + wv * 2 + 0] = (uint32_t)(m & 0xFFFFFFFFull);
    out_mask[(size_t)b * 8 + wv * 2 + 1] = (uint32_t)(m >> 32);
  }
}

// =====================================================================
// k_gemm_v (R24 c-split, passed): sums[c][b][v] for ONE c per block.
// Grid = 5120 = 5 c (major) x 1024 b-groups; block = 16 b x 512 v;
// 4 waves = 2 b-grp(8 b) x 2 v-half; thread = 8 b (4 pk pairs) x 4 v.
// Inner loop = R20-exact (h-unroll 4). Per (c,h) per wave: 2 broadcast
// ds_read_b128 + 1 dwordx4 W + 16 pk_fma. Neighbor blocks share the
// same 512KB W c-slice (c-major order) -> L2 locality.
// Chain per (b,v,c) identical to R17-R24 (bit-exact).
// =====================================================================
__global__ __launch_bounds__(256, 4) void k_gemm_v(
    const float* __restrict__ W, const uint32_t* __restrict__ mask,
    float* __restrict__ sums) {
  __shared__ uint32_t smask[16][8];
  __shared__ __align__(16) float tbf[H_DIM][16];
  int t = threadIdx.x;
  int c  = blockIdx.x >> 10;            // 0..4 (c-major)
  int b0 = (blockIdx.x & 1023) * 16;
  if (t < 128) smask[t >> 3][t & 7] = mask[(size_t)b0 * 8 + t];
  __syncthreads();
  {
    int h = t;
    uint32_t w = (uint32_t)(h >> 5), s = (uint32_t)(h & 31);
#pragma unroll
    for (int j = 0; j < 16; ++j)
      tbf[h][j] = (float)((smask[j][w] >> s) & 1u);
  }
  __syncthreads();

  int wv = t >> 6, lane = t & 63;
  int g = wv >> 1, vh = wv & 1;       // g = b-octet, vh = v-half
  int v0 = vh * 256 + (lane << 2);
  int bg = b0 + g * 8;

  f32x2 acc[4][4];
#pragma unroll
  for (int p = 0; p < 4; ++p)
#pragma unroll
    for (int q = 0; q < 4; ++q) acc[p][q] = mk2(0.f, 0.f);

  const float* wp = W + (size_t)c * (H_DIM * V_DIM) + v0;
  for (int hh = 0; hh < H_DIM; hh += 4) {
    float4 w4[4];
#pragma unroll
    for (int u = 0; u < 4; ++u)
      w4[u] = *(const float4*)(wp + (size_t)(hh + u) * V_DIM);
#pragma unroll
    for (int u = 0; u < 4; ++u) {
      const f32x4* fp = (const f32x4*)&tbf[hh + u][g * 8];
      f32x4 qA = fp[0], qB = fp[1];
      f32x2 f0 = __builtin_shufflevector(qA, qA, 0, 1);
      f32x2 f1 = __builtin_shufflevector(qA, qA, 2, 3);
      f32x2 f2 = __builtin_shufflevector(qB, qB, 0, 1);
      f32x2 f3 = __builtin_shufflevector(qB, qB, 2, 3);
      f32x2 wwx = mk2(w4[u].x, w4[u].x);
      f32x2 wwy = mk2(w4[u].y, w4[u].y);
      f32x2 wwz = mk2(w4[u].z, w4[u].z);
      f32x2 www = mk2(w4[u].w, w4[u].w);
      acc[0][0] = pkfma(wwx, f0, acc[0][0]); acc[0][1] = pkfma(wwy, f0, acc[0][1]);
      acc[0][2] = pkfma(wwz, f0, acc[0][2]); acc[0][3] = pkfma(www, f0, acc[0][3]);
      acc[1][0] = pkfma(wwx, f1, acc[1][0]); acc[1][1] = pkfma(wwy, f1, acc[1][1]);
      acc[1][2] = pkfma(wwz, f1, acc[1][2]); acc[1][3] = pkfma(www, f1, acc[1][3]);
      acc[2][0] = pkfma(wwx, f2, acc[2][0]); acc[2][1] = pkfma(wwy, f2, acc[2][1]);
      acc[2][2] = pkfma(wwz, f2, acc[2][2]); acc[2][3] = pkfma(www, f2, acc[2][3]);
      acc[3][0] = pkfma(wwx, f3, acc[3][0]); acc[3][1] = pkfma(wwy, f3, acc[3][1]);
      acc[3][2] = pkfma(wwz, f3, acc[3][2]); acc[3][3] = pkfma(www, f3, acc[3][3]);
    }
  }
  // stores: pair p covers b = bg + 2p (+1 in .y lanes)
#pragma unroll
  for (int p = 0; p < 4; ++p) {
    float4 oA, oB;
    oA.x = acc[p][0].x; oA.y = acc[p][1].x; oA.z = acc[p][2].x; oA.w = acc[p][3].x;
    oB.x = acc[p][0].y; oB.y = acc[p][1].y; oB.z = acc[p][2].y; oB.w = acc[p][3].y;
    *(float4*)&sums[((size_t)c * B_DIM + bg + 2 * p) * V_DIM + v0] = oA;
    *(float4*)&sums[((size_t)c * B_DIM + bg + 2 * p + 1) * V_DIM + v0] = oB;
  }
}

// =====================================================================
// k_gumbel_v: v = categorical over c (gumbel + first-max argmax),
// reading the staged sums. Expressions/RNG identical to R11 epilogue.
// =====================================================================
__global__ __launch_bounds__(256, 4) void k_gumbel_v(
    const float* __restrict__ sums, const float* __restrict__ b2,
    uint8_t* __restrict__ idx_out, uint32_t key0, uint32_t key1) {
  int gidx = blockIdx.x * 256 + threadIdx.x;
  int b = gidx >> 7;
  int v0 = (gidx & 127) << 2;
  float best[4];
  uint32_t bc = 0;
#pragma unroll
  for (int c = 0; c < C_DIM; ++c) {
    float4 av = *(const float4*)&sums[((size_t)c * B_DIM + b) * V_DIM + v0];
    float4 bv = *(const float4*)&b2[c * V_DIM + v0];
    uint32_t ib = ((uint32_t)b * C_DIM + (uint32_t)c) * V_DIM + (uint32_t)v0;
    float avq[4] = {av.x, av.y, av.z, av.w};
    float bvq[4] = {bv.x, bv.y, bv.z, bv.w};
#pragma unroll
    for (int q = 0; q < 4; ++q) {
      float uf = bits_to_unit_float(rng_bits(key0, key1, ib + (uint32_t)q));
      if (uf == 0.0f) uf = 1.17549435e-38f;        // u + tiny semantics
      float gz = -xla_log(-xla_log(uf));
      float z = gz + (avq[q] + bvq[q]);
      if (c == 0 || z > best[q]) {
        best[q] = z;
        bc = (bc & ~(0xFFu << (8 * q))) | ((uint32_t)c << (8 * q));
      }
    }
  }
  *(uint32_t*)(idx_out + (size_t)b * V_DIM + v0) = bc;
}

// idx -> one-hot f32 (B,C,V), float4 stores (4 v per thread)
__global__ __launch_bounds__(256) void k_onehot(const uint8_t* __restrict__ idx,
                                                float* __restrict__ out) {
  int t = blockIdx.x * 256 + threadIdx.x;     // (b*C + c)*128 + v4
  int v4 = t & 127;
  int rest = t >> 7;
  int c = rest % C_DIM;
  int b = rest / C_DIM;
  uint32_t q = *(const uint32_t*)(idx + (size_t)b * V_DIM + v4 * 4);
  uint32_t cc = (uint32_t)c;
  float4 o;
  o.x = ((q & 255u) == cc) ? 1.0f : 0.0f;
  o.y = (((q >> 8) & 255u) == cc) ? 1.0f : 0.0f;
  o.z = (((q >> 16) & 255u) == cc) ? 1.0f : 0.0f;
  o.w = (((q >> 24) & 255u) == cc) ? 1.0f : 0.0f;
  *(float4*)&out[(size_t)t * 4] = o;
}

// ---------------- launch ----------------

extern "C" void kernel_launch(void* const* d_in, const int* in_sizes, int n_in,
                              void* d_out, int out_size, void* d_ws, size_t ws_size,
                              hipStream_t stream) {
  float* out = (float*)d_out;

  // ---- structural sentinels ----
  const size_t WS_NEED = 2621440ull      // Wt
                       + 2621440ull      // (reserved, layout kept)
                       + 8388608ull      // idx
                       + 524288ull;      // mask  = 14,155,776 B
  float D = 0.0f;
  if (n_in < 4)                       D = 910.0f + (float)n_in;
  else if (in_sizes[0] != 41943040)   D = 920.0f;
  else if (in_sizes[1] != 655360)     D = 921.0f;
  else if (in_sizes[2] != 2560)       D = 922.0f;
  else if (in_sizes[3] != 256)        D = 923.0f;
  else if (out_size != 50331648)      D = 930.0f + (float)out_size * 1e-6f;
  else if (ws_size < WS_NEED)         D = 100.0f + (float)(ws_size >> 20);
  if (D != 0.0f) {
    hipLaunchKernelGGL(k_sentinel, dim3(1), dim3(1), 0, stream, out, D);
    return;
  }

  const float* v0 = (const float*)d_in[0];
  const float* W  = (const float*)d_in[1];
  const float* b2 = (const float*)d_in[2];   // (C,V)
  const float* c1 = (const float*)d_in[3];   // (H)

  float* out_v  = out;                                         // B*C*V
  float* out_h  = out + (size_t)B_DIM * C_DIM * V_DIM;         // B*H (final h)
  float* out_h0 = out_h + (size_t)B_DIM * H_DIM;               // B*H (h|v0)

  char* ws = (char*)d_ws;
  float*    Wt   = (float*)(ws);                    // 2,621,440 B
  uint8_t*  idx  = (uint8_t*)(ws + 5242880);        // 8,388,608 B
  uint32_t* mask = (uint32_t*)(ws + 13631488);      //   524,288 B

  // out_v scratch (167.77MB): partial (134.2MB at +0) + idxT (8.4MB at
  // +134.2MB) during sample_h phases; sums (full 167.77MB) during
  // gemm/gumbel (destroys idxT -> k_idxT re-runs after each gumbel).
  // Stream-ordered; k_onehot overwrites out_v last.
  float*   sums    = out_v;
  float*   partial = out_v;
  uint8_t* idxT    = (uint8_t*)out_v + 134217728ull;

  // partitionable (fold-like) split of key(42) into 5 subkeys
  uint32_t keys[5][2];
  for (int i = 0; i < 5; ++i) {
    TFOut r = tf2x32(0u, 42u, 0u, (uint32_t)i);
    keys[i][0] = r.a; keys[i][1] = r.b;
  }

  hipLaunchKernelGGL(k_wt,  dim3(2560),  dim3(256), 0, stream, W, Wt);
  hipLaunchKernelGGL(k_idx, dim3(32768), dim3(256), 0, stream, v0, idx);
  hipLaunchKernelGGL(k_idxT, dim3(2048), dim3(256), 0, stream, idx, idxT);

  // h0 = sample_h(keys[0], v0) -> h_given_v0 output + mask
  hipLaunchKernelGGL(k_hpart, dim3(4096), dim3(256), 0, stream, Wt, idxT, partial);
  hipLaunchKernelGGL(k_hfin,  dim3(B_DIM), dim3(256), 0, stream,
                     partial, c1, out_h0, mask, keys[0][0], keys[0][1]);
  // iter 0: v = sample_v(keys[1], h0); h1 = sample_h(keys[2], v)
  hipLaunchKernelGGL(k_gemm_v, dim3(B_DIM / 16 * C_DIM), dim3(256), 0, stream,
                     W, mask, sums);
  hipLaunchKernelGGL(k_gumbel_v, dim3(B_DIM * 128 / 256), dim3(256), 0, stream,
                     sums, b2, idx, keys[1][0], keys[1][1]);
  hipLaunchKernelGGL(k_idxT, dim3(2048), dim3(256), 0, stream, idx, idxT);
  hipLaunchKernelGGL(k_hpart, dim3(4096), dim3(256), 0, stream, Wt, idxT, partial);
  hipLaunchKernelGGL(k_hfin,  dim3(B_DIM), dim3(256), 0, stream,
                     partial, c1, (float*)nullptr, mask, keys[2][0], keys[2][1]);
  // iter 1: v = sample_v(keys[3], h1); h2 = sample_h(keys[4], v)
  hipLaunchKernelGGL(k_gemm_v, dim3(B_DIM / 16 * C_DIM), dim3(256), 0, stream,
                     W, mask, sums);
  hipLaunchKernelGGL(k_gumbel_v, dim3(B_DIM * 128 / 256), dim3(256), 0, stream,
                     sums, b2, idx, keys[3][0], keys[3][1]);
  hipLaunchKernelGGL(k_idxT, dim3(2048), dim3(256), 0, stream, idx, idxT);
  hipLaunchKernelGGL(k_hpart, dim3(4096), dim3(256), 0, stream, Wt, idxT, partial);
  hipLaunchKernelGGL(k_hfin,  dim3(B_DIM), dim3(256), 0, stream,
                     partial, c1, out_h, mask, keys[4][0], keys[4][1]);
  // final v one-hot output
  hipLaunchKernelGGL(k_onehot, dim3(40960), dim3(256), 0, stream, idx, out_v);
}

// Round 16
// 1846.707 us; speedup vs baseline: 1.1208x; 1.1208x over previous
//
#include <hip/hip_runtime.h>
#include <cstdint>
#include <cstddef>

// =====================================================================
// RBM Gibbs sampling, bit-exact replication of JAX-on-CPU reference.
// ROUND 26 (perf): best-of recomposition. R25 post-mortem: per-op
// inline-asm pk_fma REGRESSED (busy 203->245us, VGPR 32->40, occ
// 70->57): generic "v" constraints force operand-pair copies the
// compiler can't CSE -> revert pkfma to the builtin. Totals evidence:
// R20=1871 best; every hpart-32b config (R22-24) ~+90us; R24's
// c-split gemm_v dropped below 270 (vs R20's 285) = the one clean
// per-kernel win. So: exact R20 kernel set (hpart 64b/tbf[80][64]/
// 20KB/grid 2048/bounds(256,2), builtin pkfma, onehot float4) with
// gemm_v swapped to R24's c-split (grid 5120, one c/block, R20-exact
// inner loop). Both parts passed independently; kernels independent.
// Bit-exactness: per-(b,v)/(b,h) fma chains byte-identical (h/k
// ascending); k-split legal via sequential slab folds (tt += ps[s],
// s asc); dense +/-0.0 adds identities on never--0.0 psums; phantom
// 9th panel = +0.0; sums f32 round-trip exact; gumbel expressions/
// RNG indices identical.
// Semantics FROZEN (rounds 6-20,22-25 passed, absmax=0):
//  - threefry2x32 partitionable; fold-like split; seed(42)->(0,42).
//  - cephes-Horner exp, Pommier-Horner log (q1/q2 tail), no contract.
//  - sigmoid = 1/(1+exp(-x)) IEEE div; gumbel tiny-clamp; first-max
//    argmax; bernoulli u<p; v-GEMM K=256 single sequential chain.
//  - h-GEMM: Eigen gebp kc=320 slab fold, k ascending (c-major).
// ws layout unchanged; sentinel reads back ws_size as absmax if short.
// =====================================================================

#define B_DIM 16384
#define C_DIM 5
#define H_DIM 256
#define V_DIM 512

struct TFOut { uint32_t a, b; };

typedef float f32x2 __attribute__((ext_vector_type(2)));
typedef float f32x4 __attribute__((ext_vector_type(4)));

static __device__ inline f32x2 mk2(float x, float y) {
  f32x2 r; r.x = x; r.y = y; return r;
}

static __device__ inline f32x2 pkfma(f32x2 a, f32x2 b, f32x2 c) {
#if __has_builtin(__builtin_elementwise_fma)
  return __builtin_elementwise_fma(a, b, c);
#else
  f32x2 r; r.x = fmaf(a.x, b.x, c.x); r.y = fmaf(a.y, b.y, c.y); return r;
#endif
}

__host__ __device__ static inline TFOut tf2x32(uint32_t k0, uint32_t k1,
                                               uint32_t c0, uint32_t c1) {
  uint32_t ks2 = k0 ^ k1 ^ 0x1BD11BDAu;
  uint32_t x0 = c0 + k0, x1 = c1 + k1;
#define TF_R(r) { x0 += x1; x1 = (x1 << r) | (x1 >> (32 - r)); x1 ^= x0; }
  TF_R(13) TF_R(15) TF_R(26) TF_R(6)
  x0 += k1;  x1 += ks2 + 1u;
  TF_R(17) TF_R(29) TF_R(16) TF_R(24)
  x0 += ks2; x1 += k0 + 2u;
  TF_R(13) TF_R(15) TF_R(26) TF_R(6)
  x0 += k0;  x1 += k1 + 3u;
  TF_R(17) TF_R(29) TF_R(16) TF_R(24)
  x0 += k1;  x1 += ks2 + 4u;
  TF_R(13) TF_R(15) TF_R(26) TF_R(6)
  x0 += ks2; x1 += k0 + 5u;
#undef TF_R
  TFOut o; o.a = x0; o.b = x1; return o;
}

// partitionable random_bits, 32-bit width, element index i (< 2^32)
__device__ static inline uint32_t rng_bits(uint32_t k0, uint32_t k1, uint32_t i) {
  TFOut r = tf2x32(k0, k1, 0u, i);
  return r.a ^ r.b;
}

__device__ static inline float bits_to_unit_float(uint32_t bits) {
  return __uint_as_float((bits >> 9) | 0x3F800000u) - 1.0f;
}

// XLA GenerateVF32Exp replica (cephes Horner port), mul+add separate,
// NO contraction.
__device__ static float xla_exp(float x_in) {
#pragma clang fp contract(off)
  float x = fminf(x_in, 88.3762626647950f);
  x = fmaxf(x, -88.3762626647949f);
  float fx = floorf(x * 1.44269504088896341f + 0.5f);
  float tmp = fx * 0.693359375f;
  float z = fx * -2.12194440e-4f;
  x = x - tmp;
  x = x - z;
  z = x * x;
  float y = 1.9875691500e-4f;
  y = y * x + 1.3981999507e-3f;
  y = y * x + 8.3334519073e-3f;
  y = y * x + 4.1665795894e-2f;
  y = y * x + 1.6666665459e-1f;
  y = y * x + 5.0000001201e-1f;
  y = y * z + x;
  y = y + 1.0f;
  int n = (int)fx;
  y = y * __uint_as_float((uint32_t)(n + 127) << 23);
  return y;
}

// XLA GenerateVF32Log replica = Pommier/Eigen3.3 log_ps (Horner + tail:
// y+=e*q1; y-=0.5*z; x+=y; x+=e*q2). NO contraction.
__device__ static float xla_log(float x_in) {
#pragma clang fp contract(off)
  float xv = fmaxf(x_in, 1.17549435e-38f);      // min_norm_pos clamp
  uint32_t bits = __float_as_uint(xv);
  float e = (float)((int)(bits >> 23) - 126);
  float x = __uint_as_float((bits & 0x007FFFFFu) | 0x3F000000u);  // [0.5,1)
  bool m = (x < 0.707106781186547524f);
  float tmp = m ? x : 0.0f;
  x = x - 1.0f;
  e = e - (m ? 1.0f : 0.0f);
  x = x + tmp;
  float z = x * x;
  float y = 7.0376836292e-2f;
  y = y * x + -1.1514610310e-1f;
  y = y * x + 1.1676998740e-1f;
  y = y * x + -1.2420140846e-1f;
  y = y * x + 1.4249322787e-1f;
  y = y * x + -1.6668057665e-1f;
  y = y * x + 2.0000714765e-1f;
  y = y * x + -2.4999993993e-1f;
  y = y * x + 3.3333331174e-1f;
  y = y * x;
  y = y * z;
  float t1 = e * -2.12194440e-4f;
  y = y + t1;
  float t2 = z * 0.5f;
  y = y - t2;
  x = x + y;
  float t3 = e * 0.693359375f;
  x = x + t3;
  return x;
}

// ---------------- kernels ----------------

__global__ void k_sentinel(float* out, float d) {
  out[0] = d;
}

// v0 one-hot (B,C,V) -> idx (B,V) u8
__global__ __launch_bounds__(256) void k_idx(const float* __restrict__ v0,
                                             uint8_t* __restrict__ idx) {
  int t = blockIdx.x * 256 + threadIdx.x;          // b*V + v
  int b = t >> 9, v = t & 511;
  const float* p = v0 + (size_t)b * (C_DIM * V_DIM) + v;
  int cf = 0;
#pragma unroll
  for (int c = 0; c < C_DIM; ++c)
    if (p[c * V_DIM] > 0.5f) cf = c;
  idx[t] = (uint8_t)cf;
}

// idx (B,V) u8 -> idxT (V,B) u8 via 64x64 LDS tiles (coalesced both ways)
__global__ __launch_bounds__(256) void k_idxT(const uint8_t* __restrict__ idx,
                                              uint8_t* __restrict__ idxT) {
  __shared__ uint8_t tile[64][68];
  int t = threadIdx.x;
  int bb = blockIdx.x >> 3, vv = blockIdx.x & 7;
  int b0 = bb * 64, v0 = vv * 64;
  for (int i = t; i < 1024; i += 256) {        // 64 b-rows x 16 u32
    int r = i >> 4, wc = i & 15;
    uint32_t q = *(const uint32_t*)(idx + (size_t)(b0 + r) * V_DIM + v0 + wc * 4);
    int v = wc * 4;
    tile[v + 0][r] = (uint8_t)(q);
    tile[v + 1][r] = (uint8_t)(q >> 8);
    tile[v + 2][r] = (uint8_t)(q >> 16);
    tile[v + 3][r] = (uint8_t)(q >> 24);
  }
  __syncthreads();
  for (int i = t; i < 1024; i += 256) {        // 64 v-rows x 16 u32
    int vr = i >> 4, wc = i & 15;
    uint32_t q = (uint32_t)tile[vr][wc * 4]
               | ((uint32_t)tile[vr][wc * 4 + 1] << 8)
               | ((uint32_t)tile[vr][wc * 4 + 2] << 16)
               | ((uint32_t)tile[vr][wc * 4 + 3] << 24);
    *(uint32_t*)(idxT + (size_t)(v0 + vr) * B_DIM + b0 + wc * 4) = q;
  }
}

// W (c,h,v) -> Wt (c,v,h)
__global__ __launch_bounds__(256) void k_wt(const float* __restrict__ W,
                                            float* __restrict__ Wt) {
  int t = blockIdx.x * 256 + threadIdx.x;          // (c, v, h)
  int h = t & 255; int rest = t >> 8; int v = rest & 511; int c = rest >> 9;
  Wt[t] = W[((size_t)c * H_DIM + h) * V_DIM + v];
}

// =====================================================================
// k_hpart (R20 64b version, best total): partial[s][b][h] = dense
// k-ascending fma psum over slab s, f = (idxT[k&511][b] == k>>9).
// Block = 64 b x 256 h x 1 slab; thread = 16 b (8 pk pairs) x 4 h.
// Grid 2048 = 256 b-groups x 8 slabs. tbf[80][64] = 20KB LDS.
// psum carries across the 4 sub-tiles (folds only at slab=block
// boundaries) -- chain per (b,h) identical to R18-R25.
// =====================================================================
__global__ __launch_bounds__(256, 2) void k_hpart(
    const float* __restrict__ Wt, const uint8_t* __restrict__ idxT,
    float* __restrict__ partial) {
  __shared__ __align__(16) float tbf[80][64];    // f-floats, one k-tile
  int t = threadIdx.x;
  int bg = blockIdx.x >> 3, s = blockIdx.x & 7;
  int b0 = bg * 64;
  int wv = t >> 6, lane = t & 63;
  int g16 = wv * 16;

  f32x2 ps[4][8];
#pragma unroll
  for (int hq = 0; hq < 4; ++hq)
#pragma unroll
    for (int p = 0; p < 8; ++p) ps[hq][p] = mk2(0.f, 0.f);

  for (int tau = 0; tau < 4; ++tau) {
    int kbase = s * 320 + tau * 80;
    // ---- expand f-floats for this tile (coalesced idxT reads) ----
    {
      int kk0 = t >> 4, bq = t & 15;
#pragma unroll
      for (int i = 0; i < 5; ++i) {
        int kk = kk0 + 16 * i;
        int k = kbase + kk;
        int v = k & 511;
        uint32_t cc = (uint32_t)(k >> 9);
        uint32_t q = *(const uint32_t*)(idxT + (size_t)v * B_DIM + b0 + bq * 4);
        float4 o;
        o.x = ((q & 255u) == cc) ? 1.0f : 0.0f;
        o.y = (((q >> 8) & 255u) == cc) ? 1.0f : 0.0f;
        o.z = (((q >> 16) & 255u) == cc) ? 1.0f : 0.0f;
        o.w = (((q >> 24) & 255u) == cc) ? 1.0f : 0.0f;
        *(float4*)&tbf[kk][bq * 4] = o;
      }
    }
    __syncthreads();
    // ---- dense accumulate over the tile, k ascending ----
#pragma unroll 2
    for (int kk = 0; kk < 80; ++kk) {
      int k = kbase + kk;
      float4 w = *(const float4*)(Wt + (size_t)k * H_DIM + (lane << 2));
      const f32x4* fp = (const f32x4*)&tbf[kk][g16];
      f32x4 qA = fp[0], qB = fp[1], qC = fp[2], qD = fp[3];
      f32x2 f0 = __builtin_shufflevector(qA, qA, 0, 1);
      f32x2 f1 = __builtin_shufflevector(qA, qA, 2, 3);
      f32x2 f2 = __builtin_shufflevector(qB, qB, 0, 1);
      f32x2 f3 = __builtin_shufflevector(qB, qB, 2, 3);
      f32x2 f4 = __builtin_shufflevector(qC, qC, 0, 1);
      f32x2 f5 = __builtin_shufflevector(qC, qC, 2, 3);
      f32x2 f6 = __builtin_shufflevector(qD, qD, 0, 1);
      f32x2 f7 = __builtin_shufflevector(qD, qD, 2, 3);
      f32x2 w0 = mk2(w.x, w.x);
      f32x2 w1 = mk2(w.y, w.y);
      f32x2 w2 = mk2(w.z, w.z);
      f32x2 w3 = mk2(w.w, w.w);
      ps[0][0] = pkfma(w0, f0, ps[0][0]); ps[1][0] = pkfma(w1, f0, ps[1][0]);
      ps[2][0] = pkfma(w2, f0, ps[2][0]); ps[3][0] = pkfma(w3, f0, ps[3][0]);
      ps[0][1] = pkfma(w0, f1, ps[0][1]); ps[1][1] = pkfma(w1, f1, ps[1][1]);
      ps[2][1] = pkfma(w2, f1, ps[2][1]); ps[3][1] = pkfma(w3, f1, ps[3][1]);
      ps[0][2] = pkfma(w0, f2, ps[0][2]); ps[1][2] = pkfma(w1, f2, ps[1][2]);
      ps[2][2] = pkfma(w2, f2, ps[2][2]); ps[3][2] = pkfma(w3, f2, ps[3][2]);
      ps[0][3] = pkfma(w0, f3, ps[0][3]); ps[1][3] = pkfma(w1, f3, ps[1][3]);
      ps[2][3] = pkfma(w2, f3, ps[2][3]); ps[3][3] = pkfma(w3, f3, ps[3][3]);
      ps[0][4] = pkfma(w0, f4, ps[0][4]); ps[1][4] = pkfma(w1, f4, ps[1][4]);
      ps[2][4] = pkfma(w2, f4, ps[2][4]); ps[3][4] = pkfma(w3, f4, ps[3][4]);
      ps[0][5] = pkfma(w0, f5, ps[0][5]); ps[1][5] = pkfma(w1, f5, ps[1][5]);
      ps[2][5] = pkfma(w2, f5, ps[2][5]); ps[3][5] = pkfma(w3, f5, ps[3][5]);
      ps[0][6] = pkfma(w0, f6, ps[0][6]); ps[1][6] = pkfma(w1, f6, ps[1][6]);
      ps[2][6] = pkfma(w2, f6, ps[2][6]); ps[3][6] = pkfma(w3, f6, ps[3][6]);
      ps[0][7] = pkfma(w0, f7, ps[0][7]); ps[1][7] = pkfma(w1, f7, ps[1][7]);
      ps[2][7] = pkfma(w2, f7, ps[2][7]); ps[3][7] = pkfma(w3, f7, ps[3][7]);
    }
    __syncthreads();   // tbf reads done before next tile's expand
  }

  // ---- store partials: pair p covers b = b0+g16+2p (+1 in .y) ----
  int h0 = lane << 2;
#pragma unroll
  for (int p = 0; p < 8; ++p) {
    float4 oA, oB;
    oA.x = ps[0][p].x; oA.y = ps[1][p].x; oA.z = ps[2][p].x; oA.w = ps[3][p].x;
    oB.x = ps[0][p].y; oB.y = ps[1][p].y; oB.z = ps[2][p].y; oB.w = ps[3][p].y;
    int bA = b0 + g16 + 2 * p;
    *(float4*)&partial[((size_t)s * B_DIM + bA) * H_DIM + h0] = oA;
    *(float4*)&partial[((size_t)s * B_DIM + bA + 1) * H_DIM + h0] = oB;
  }
}

// =====================================================================
// k_hfin: fold the 8 slab partials in s-ascending order (exact R11
// chain: tt starts 0, tt += ps[s]; phantom 9th panel = +0.0 identity),
// then sigmoid + bernoulli + out_h + mask (R11 epilogue verbatim).
// =====================================================================
__global__ __launch_bounds__(256) void k_hfin(
    const float* __restrict__ partial, const float* __restrict__ c1,
    float* __restrict__ out_h, uint32_t* __restrict__ out_mask,
    uint32_t key0, uint32_t key1) {
  int b = blockIdx.x;
  int t = threadIdx.x;
  int wv = t >> 6;
  float tt = 0.0f;
#pragma unroll
  for (int s = 0; s < 8; ++s)
    tt = tt + partial[((size_t)s * B_DIM + b) * H_DIM + t];

  float tot = tt + c1[t];
  float p = 1.0f / (1.0f + xla_exp(-tot));   // IEEE div, logistic exp form

  uint32_t i = (uint32_t)(b * H_DIM + t);
  float u = bits_to_unit_float(rng_bits(key0, key1, i));
  bool hb = (u < p);
  if (out_h) out_h[(size_t)b * H_DIM + t] = hb ? 1.0f : 0.0f;

  unsigned long long m = __ballot(hb);
  if ((t & 63) == 0) {
    out_mask[(size_t)b * 8 + wv * 2 + 0] = (uint32_t)(m & 0xFFFFFFFFull);
    out_mask[(size_t)b * 8 + wv * 2 + 1] = (uint32_t)(m >> 32);
  }
}

// =====================================================================
// k_gemm_v (R24 c-split, passed, < 270us): sums[c][b][v], ONE c/block.
// Grid = 5120 = 5 c (major) x 1024 b-groups; block = 16 b x 512 v;
// 4 waves = 2 b-grp(8 b) x 2 v-half; thread = 8 b (4 pk pairs) x 4 v.
// Inner loop = R20-exact (h-unroll 4). Per (c,h) per wave: 2 broadcast
// ds_read_b128 + 1 dwordx4 W + 16 pk_fma. Neighbor blocks share the
// same 512KB W c-slice (c-major order) -> L2 locality.
// Chain per (b,v,c) identical to R17-R25 (bit-exact).
// =====================================================================
__global__ __launch_bounds__(256, 4) void k_gemm_v(
    const float* __restrict__ W, const uint32_t* __restrict__ mask,
    float* __restrict__ sums) {
  __shared__ uint32_t smask[16][8];
  __shared__ __align__(16) float tbf[H_DIM][16];
  int t = threadIdx.x;
  int c  = blockIdx.x >> 10;            // 0..4 (c-major)
  int b0 = (blockIdx.x & 1023) * 16;
  if (t < 128) smask[t >> 3][t & 7] = mask[(size_t)b0 * 8 + t];
  __syncthreads();
  {
    int h = t;
    uint32_t w = (uint32_t)(h >> 5), s = (uint32_t)(h & 31);
#pragma unroll
    for (int j = 0; j < 16; ++j)
      tbf[h][j] = (float)((smask[j][w] >> s) & 1u);
  }
  __syncthreads();

  int wv = t >> 6, lane = t & 63;
  int g = wv >> 1, vh = wv & 1;       // g = b-octet, vh = v-half
  int v0 = vh * 256 + (lane << 2);
  int bg = b0 + g * 8;

  f32x2 acc[4][4];
#pragma unroll
  for (int p = 0; p < 4; ++p)
#pragma unroll
    for (int q = 0; q < 4; ++q) acc[p][q] = mk2(0.f, 0.f);

  const float* wp = W + (size_t)c * (H_DIM * V_DIM) + v0;
  for (int hh = 0; hh < H_DIM; hh += 4) {
    float4 w4[4];
#pragma unroll
    for (int u = 0; u < 4; ++u)
      w4[u] = *(const float4*)(wp + (size_t)(hh + u) * V_DIM);
#pragma unroll
    for (int u = 0; u < 4; ++u) {
      const f32x4* fp = (const f32x4*)&tbf[hh + u][g * 8];
      f32x4 qA = fp[0], qB = fp[1];
      f32x2 f0 = __builtin_shufflevector(qA, qA, 0, 1);
      f32x2 f1 = __builtin_shufflevector(qA, qA, 2, 3);
      f32x2 f2 = __builtin_shufflevector(qB, qB, 0, 1);
      f32x2 f3 = __builtin_shufflevector(qB, qB, 2, 3);
      f32x2 wwx = mk2(w4[u].x, w4[u].x);
      f32x2 wwy = mk2(w4[u].y, w4[u].y);
      f32x2 wwz = mk2(w4[u].z, w4[u].z);
      f32x2 www = mk2(w4[u].w, w4[u].w);
      acc[0][0] = pkfma(wwx, f0, acc[0][0]); acc[0][1] = pkfma(wwy, f0, acc[0][1]);
      acc[0][2] = pkfma(wwz, f0, acc[0][2]); acc[0][3] = pkfma(www, f0, acc[0][3]);
      acc[1][0] = pkfma(wwx, f1, acc[1][0]); acc[1][1] = pkfma(wwy, f1, acc[1][1]);
      acc[1][2] = pkfma(wwz, f1, acc[1][2]); acc[1][3] = pkfma(www, f1, acc[1][3]);
      acc[2][0] = pkfma(wwx, f2, acc[2][0]); acc[2][1] = pkfma(wwy, f2, acc[2][1]);
      acc[2][2] = pkfma(wwz, f2, acc[2][2]); acc[2][3] = pkfma(www, f2, acc[2][3]);
      acc[3][0] = pkfma(wwx, f3, acc[3][0]); acc[3][1] = pkfma(wwy, f3, acc[3][1]);
      acc[3][2] = pkfma(wwz, f3, acc[3][2]); acc[3][3] = pkfma(www, f3, acc[3][3]);
    }
  }
  // stores: pair p covers b = bg + 2p (+1 in .y lanes)
#pragma unroll
  for (int p = 0; p < 4; ++p) {
    float4 oA, oB;
    oA.x = acc[p][0].x; oA.y = acc[p][1].x; oA.z = acc[p][2].x; oA.w = acc[p][3].x;
    oB.x = acc[p][0].y; oB.y = acc[p][1].y; oB.z = acc[p][2].y; oB.w = acc[p][3].y;
    *(float4*)&sums[((size_t)c * B_DIM + bg + 2 * p) * V_DIM + v0] = oA;
    *(float4*)&sums[((size_t)c * B_DIM + bg + 2 * p + 1) * V_DIM + v0] = oB;
  }
}

// =====================================================================
// k_gumbel_v: v = categorical over c (gumbel + first-max argmax),
// reading the staged sums. Expressions/RNG identical to R11 epilogue.
// =====================================================================
__global__ __launch_bounds__(256, 4) void k_gumbel_v(
    const float* __restrict__ sums, const float* __restrict__ b2,
    uint8_t* __restrict__ idx_out, uint32_t key0, uint32_t key1) {
  int gidx = blockIdx.x * 256 + threadIdx.x;
  int b = gidx >> 7;
  int v0 = (gidx & 127) << 2;
  float best[4];
  uint32_t bc = 0;
#pragma unroll
  for (int c = 0; c < C_DIM; ++c) {
    float4 av = *(const float4*)&sums[((size_t)c * B_DIM + b) * V_DIM + v0];
    float4 bv = *(const float4*)&b2[c * V_DIM + v0];
    uint32_t ib = ((uint32_t)b * C_DIM + (uint32_t)c) * V_DIM + (uint32_t)v0;
    float avq[4] = {av.x, av.y, av.z, av.w};
    float bvq[4] = {bv.x, bv.y, bv.z, bv.w};
#pragma unroll
    for (int q = 0; q < 4; ++q) {
      float uf = bits_to_unit_float(rng_bits(key0, key1, ib + (uint32_t)q));
      if (uf == 0.0f) uf = 1.17549435e-38f;        // u + tiny semantics
      float gz = -xla_log(-xla_log(uf));
      float z = gz + (avq[q] + bvq[q]);
      if (c == 0 || z > best[q]) {
        best[q] = z;
        bc = (bc & ~(0xFFu << (8 * q))) | ((uint32_t)c << (8 * q));
      }
    }
  }
  *(uint32_t*)(idx_out + (size_t)b * V_DIM + v0) = bc;
}

// idx -> one-hot f32 (B,C,V), float4 stores (4 v per thread)
__global__ __launch_bounds__(256) void k_onehot(const uint8_t* __restrict__ idx,
                                                float* __restrict__ out) {
  int t = blockIdx.x * 256 + threadIdx.x;     // (b*C + c)*128 + v4
  int v4 = t & 127;
  int rest = t >> 7;
  int c = rest % C_DIM;
  int b = rest / C_DIM;
  uint32_t q = *(const uint32_t*)(idx + (size_t)b * V_DIM + v4 * 4);
  uint32_t cc = (uint32_t)c;
  float4 o;
  o.x = ((q & 255u) == cc) ? 1.0f : 0.0f;
  o.y = (((q >> 8) & 255u) == cc) ? 1.0f : 0.0f;
  o.z = (((q >> 16) & 255u) == cc) ? 1.0f : 0.0f;
  o.w = (((q >> 24) & 255u) == cc) ? 1.0f : 0.0f;
  *(float4*)&out[(size_t)t * 4] = o;
}

// ---------------- launch ----------------

extern "C" void kernel_launch(void* const* d_in, const int* in_sizes, int n_in,
                              void* d_out, int out_size, void* d_ws, size_t ws_size,
                              hipStream_t stream) {
  float* out = (float*)d_out;

  // ---- structural sentinels ----
  const size_t WS_NEED = 2621440ull      // Wt
                       + 2621440ull      // (reserved, layout kept)
                       + 8388608ull      // idx
                       + 524288ull;      // mask  = 14,155,776 B
  float D = 0.0f;
  if (n_in < 4)                       D = 910.0f + (float)n_in;
  else if (in_sizes[0] != 41943040)   D = 920.0f;
  else if (in_sizes[1] != 655360)     D = 921.0f;
  else if (in_sizes[2] != 2560)       D = 922.0f;
  else if (in_sizes[3] != 256)        D = 923.0f;
  else if (out_size != 50331648)      D = 930.0f + (float)out_size * 1e-6f;
  else if (ws_size < WS_NEED)         D = 100.0f + (float)(ws_size >> 20);
  if (D != 0.0f) {
    hipLaunchKernelGGL(k_sentinel, dim3(1), dim3(1), 0, stream, out, D);
    return;
  }

  const float* v0 = (const float*)d_in[0];
  const float* W  = (const float*)d_in[1];
  const float* b2 = (const float*)d_in[2];   // (C,V)
  const float* c1 = (const float*)d_in[3];   // (H)

  float* out_v  = out;                                         // B*C*V
  float* out_h  = out + (size_t)B_DIM * C_DIM * V_DIM;         // B*H (final h)
  float* out_h0 = out_h + (size_t)B_DIM * H_DIM;               // B*H (h|v0)

  char* ws = (char*)d_ws;
  float*    Wt   = (float*)(ws);                    // 2,621,440 B
  uint8_t*  idx  = (uint8_t*)(ws + 5242880);        // 8,388,608 B
  uint32_t* mask = (uint32_t*)(ws + 13631488);      //   524,288 B

  // out_v scratch (167.77MB): partial (134.2MB at +0) + idxT (8.4MB at
  // +134.2MB) during sample_h phases; sums (full 167.77MB) during
  // gemm/gumbel (destroys idxT -> k_idxT re-runs after each gumbel).
  // Stream-ordered; k_onehot overwrites out_v last.
  float*   sums    = out_v;
  float*   partial = out_v;
  uint8_t* idxT    = (uint8_t*)out_v + 134217728ull;

  // partitionable (fold-like) split of key(42) into 5 subkeys
  uint32_t keys[5][2];
  for (int i = 0; i < 5; ++i) {
    TFOut r = tf2x32(0u, 42u, 0u, (uint32_t)i);
    keys[i][0] = r.a; keys[i][1] = r.b;
  }

  hipLaunchKernelGGL(k_wt,  dim3(2560),  dim3(256), 0, stream, W, Wt);
  hipLaunchKernelGGL(k_idx, dim3(32768), dim3(256), 0, stream, v0, idx);
  hipLaunchKernelGGL(k_idxT, dim3(2048), dim3(256), 0, stream, idx, idxT);

  // h0 = sample_h(keys[0], v0) -> h_given_v0 output + mask
  hipLaunchKernelGGL(k_hpart, dim3(2048), dim3(256), 0, stream, Wt, idxT, partial);
  hipLaunchKernelGGL(k_hfin,  dim3(B_DIM), dim3(256), 0, stream,
                     partial, c1, out_h0, mask, keys[0][0], keys[0][1]);
  // iter 0: v = sample_v(keys[1], h0); h1 = sample_h(keys[2], v)
  hipLaunchKernelGGL(k_gemm_v, dim3(B_DIM / 16 * C_DIM), dim3(256), 0, stream,
                     W, mask, sums);
  hipLaunchKernelGGL(k_gumbel_v, dim3(B_DIM * 128 / 256), dim3(256), 0, stream,
                     sums, b2, idx, keys[1][0], keys[1][1]);
  hipLaunchKernelGGL(k_idxT, dim3(2048), dim3(256), 0, stream, idx, idxT);
  hipLaunchKernelGGL(k_hpart, dim3(2048), dim3(256), 0, stream, Wt, idxT, partial);
  hipLaunchKernelGGL(k_hfin,  dim3(B_DIM), dim3(256), 0, stream,
                     partial, c1, (float*)nullptr, mask, keys[2][0], keys[2][1]);
  // iter 1: v = sample_v(keys[3], h1); h2 = sample_h(keys[4], v)
  hipLaunchKernelGGL(k_gemm_v, dim3(B_DIM / 16 * C_DIM), dim3(256), 0, stream,
                     W, mask, sums);
  hipLaunchKernelGGL(k_gumbel_v, dim3(B_DIM * 128 / 256), dim3(256), 0, stream,
                     sums, b2, idx, keys[3][0], keys[3][1]);
  hipLaunchKernelGGL(k_idxT, dim3(2048), dim3(256), 0, stream, idx, idxT);
  hipLaunchKernelGGL(k_hpart, dim3(2048), dim3(256), 0, stream, Wt, idxT, partial);
  hipLaunchKernelGGL(k_hfin,  dim3(B_DIM), dim3(256), 0, stream,
                     partial, c1, out_h, mask, keys[4][0], keys[4][1]);
  // final v one-hot output
  hipLaunchKernelGGL(k_onehot, dim3(40960), dim3(256), 0, stream, idx, out_v);
}